// Round 7
// baseline (646.920 us; speedup 1.0000x reference)
//
#include <hip/hip_runtime.h>
#include <math.h>

// SSCA restructured; all big contractions = split-bf16 (hi+lo, 3-MFMA) on matrix pipe.
//   WfH/L   = cvt(Wf)          [c][f]      (pre-converted, ws)
//   W1TH/L  = cvt(Wf1^T)       [c][f]
//   QT      = (queries@Wq+bq)^T hi/lo [ba][cp]   (barrier-free GEMM)
//   bQ      = bf . Q
//   FQT     = (Wf@Q)^T hi/lo [ba][c]      (barrier-free 64x128 GEMM, K-split x2 + combine)
//   sp      = feat@FQ partials fp32, K-split x2   (barrier-free GEMM)
//   attn    = softmax((sp0+sp1+bQ)/8) -> d_out fp32 + attnT hi/lo [ba][n] + L-partials
//   TT      = (feat^T@attn)^T hi/lo [ba][f]  (LDS-transpose GEMM)
//   out     = Wf1^T@T + bf1 (x) L          (barrier-free 64x128 GEMM, K-split x2 + combine)

#define CCH 2048
#define HWD 1024
#define DQD 512
#define NA  64

typedef __attribute__((ext_vector_type(8))) short bf16x8;
typedef __attribute__((ext_vector_type(4))) float f32x4;
typedef __attribute__((ext_vector_type(4))) unsigned short us4;
typedef __attribute__((ext_vector_type(8))) unsigned short us8;

__device__ __forceinline__ unsigned short bfhi(float v) {
    return (unsigned short)(__float_as_uint(v) >> 16);
}
__device__ __forceinline__ float bfres(float v) {
    return v - __uint_as_float(__float_as_uint(v) & 0xffff0000u);
}
__device__ __forceinline__ float bf2f(unsigned short h) {
    return __uint_as_float(((unsigned)h) << 16);
}

#define MFMA(A, B, C) __builtin_amdgcn_mfma_f32_16x16x32_bf16((A), (B), (C), 0, 0, 0)

// ---------- converts ----------
__global__ __launch_bounds__(256) void k_convWf(const float* __restrict__ in,
    unsigned short* __restrict__ hi, unsigned short* __restrict__ lo)
{
    int i = blockIdx.x * 256 + threadIdx.x;
    float4 v = ((const float4*)in)[i];
    us4 h, l;
    float a[4] = {v.x, v.y, v.z, v.w};
#pragma unroll
    for (int j = 0; j < 4; ++j) { h[j] = bfhi(a[j]); l[j] = bfhi(bfres(a[j])); }
    ((us4*)hi)[i] = h;
    ((us4*)lo)[i] = l;
}

__global__ __launch_bounds__(256) void k_convT(const float* __restrict__ in,
    unsigned short* __restrict__ hi, unsigned short* __restrict__ lo)
{
    __shared__ float t[64][65];
    const int tid = threadIdx.x;
    const int f0 = blockIdx.x * 64, c0 = blockIdx.y * 64;
#pragma unroll
    for (int r = 0; r < 4; ++r) {
        int fr = (tid >> 4) + r * 16;
        int cc = (tid & 15) * 4;
        float4 v = *(const float4*)&in[(size_t)(f0 + fr) * CCH + c0 + cc];
        t[fr][cc] = v.x; t[fr][cc + 1] = v.y; t[fr][cc + 2] = v.z; t[fr][cc + 3] = v.w;
    }
    __syncthreads();
#pragma unroll
    for (int r = 0; r < 2; ++r) {
        int c = (tid >> 3) + r * 32;
        int g = tid & 7;
        us8 h8, l8;
#pragma unroll
        for (int j = 0; j < 8; ++j) {
            float v = t[g * 8 + j][c];
            h8[j] = bfhi(v); l8[j] = bfhi(bfres(v));
        }
        *(us8*)&hi[(size_t)(c0 + c) * CCH + f0 + g * 8] = h8;
        *(us8*)&lo[(size_t)(c0 + c) * CCH + f0 + g * 8] = l8;
    }
}

__global__ __launch_bounds__(256) void k_convWq(const float* __restrict__ Wq,
    unsigned short* __restrict__ hi, unsigned short* __restrict__ lo)
{
    __shared__ float t[64][65];
    const int tid = threadIdx.x;
    const int k0 = blockIdx.x * 64;
#pragma unroll
    for (int r = 0; r < 4; ++r) {
        int kr = (tid >> 4) + r * 16;
        int cc = (tid & 15) * 4;
        float4 v = *(const float4*)&Wq[(size_t)(k0 + kr) * NA + cc];
        t[kr][cc] = v.x; t[kr][cc + 1] = v.y; t[kr][cc + 2] = v.z; t[kr][cc + 3] = v.w;
    }
    __syncthreads();
#pragma unroll
    for (int r = 0; r < 2; ++r) {
        int a = (tid >> 3) + r * 32;
        int g = tid & 7;
        us8 h8, l8;
#pragma unroll
        for (int j = 0; j < 8; ++j) {
            float v = t[g * 8 + j][a];
            h8[j] = bfhi(v); l8[j] = bfhi(bfres(v));
        }
        *(us8*)&hi[(size_t)a * DQD + k0 + g * 8] = h8;
        *(us8*)&lo[(size_t)a * DQD + k0 + g * 8] = l8;
    }
}

// ---------- weight GEMM, barrier-free, 64m x 128n block (4 waves as 2x2), K-split x2 ----
// A hi/lo [2048][2048] k-contig, B hi/lo [1024][2048] k-contig.
// EPI 0 (FQ):  P[z][n][m]  (row stride CCH)   -- float4 stores
// EPI 1 (out): P[z][m][n]  (row stride 1024)  -- scalar stores, lane-coalesced
template <int EPI>
__global__ __launch_bounds__(256) void k_gemm_ks(
    const unsigned short* __restrict__ Ah, const unsigned short* __restrict__ Al,
    const unsigned short* __restrict__ Bh, const unsigned short* __restrict__ Bl,
    float* __restrict__ P)
{
    const int tid = threadIdx.x, w = tid >> 6, l = tid & 63, lr = l & 15, lg = l >> 4;
    const int wm = w & 1, wn = w >> 1;
    const int m0 = blockIdx.x * 64 + wm * 32;
    const int n0 = blockIdx.y * 128 + wn * 64;
    const int koff = blockIdx.z * 1024;
    float* Pz = P + (size_t)blockIdx.z * (2048u * 1024u);

    const bf16x8* pA0h = (const bf16x8*)(Ah + (size_t)(m0 + lr) * CCH + koff) + lg;
    const bf16x8* pA0l = (const bf16x8*)(Al + (size_t)(m0 + lr) * CCH + koff) + lg;
    const bf16x8* pA1h = (const bf16x8*)(Ah + (size_t)(m0 + 16 + lr) * CCH + koff) + lg;
    const bf16x8* pA1l = (const bf16x8*)(Al + (size_t)(m0 + 16 + lr) * CCH + koff) + lg;
    const bf16x8* pBh[4];
    const bf16x8* pBl[4];
#pragma unroll
    for (int nf = 0; nf < 4; ++nf) {
        pBh[nf] = (const bf16x8*)(Bh + (size_t)(n0 + nf * 16 + lr) * CCH + koff) + lg;
        pBl[nf] = (const bf16x8*)(Bl + (size_t)(n0 + nf * 16 + lr) * CCH + koff) + lg;
    }

    f32x4 acc[2][4];
#pragma unroll
    for (int mi = 0; mi < 2; ++mi)
#pragma unroll
        for (int nf = 0; nf < 4; ++nf) acc[mi][nf] = (f32x4){0.f, 0.f, 0.f, 0.f};

#pragma unroll 2
    for (int it = 0; it < 32; ++it) {
        bf16x8 a0h = *pA0h, a0l = *pA0l, a1h = *pA1h, a1l = *pA1l;
        pA0h += 4; pA0l += 4; pA1h += 4; pA1l += 4;
#pragma unroll
        for (int nf = 0; nf < 4; ++nf) {
            bf16x8 bh = *pBh[nf], bl = *pBl[nf];
            pBh[nf] += 4; pBl[nf] += 4;
            acc[0][nf] = MFMA(a0h, bh, acc[0][nf]);
            acc[0][nf] = MFMA(a0h, bl, acc[0][nf]);
            acc[0][nf] = MFMA(a0l, bh, acc[0][nf]);
            acc[1][nf] = MFMA(a1h, bh, acc[1][nf]);
            acc[1][nf] = MFMA(a1h, bl, acc[1][nf]);
            acc[1][nf] = MFMA(a1l, bh, acc[1][nf]);
        }
    }

#pragma unroll
    for (int mi = 0; mi < 2; ++mi) {
        const int mrow0 = m0 + mi * 16 + lg * 4;
#pragma unroll
        for (int nf = 0; nf < 4; ++nf) {
            const int nn = n0 + nf * 16 + lr;
            if (EPI == 0) {
                *(f32x4*)&Pz[(size_t)nn * CCH + mrow0] = acc[mi][nf];
            } else {
#pragma unroll
                for (int j = 0; j < 4; ++j)
                    Pz[(size_t)(mrow0 + j) * 1024 + nn] = acc[mi][nf][j];
            }
        }
    }
}

// ---------- FQ combine: FQT hi/lo[ba][c] = cvt(P0 + P1) ----------
__global__ __launch_bounds__(256) void k_fqcomb(const float* __restrict__ P,
    unsigned short* __restrict__ FQh, unsigned short* __restrict__ FQl)
{
    int i = blockIdx.x * 256 + threadIdx.x;            // one float4 (524288 total)
    float4 v0 = ((const float4*)P)[i];
    float4 v1 = ((const float4*)P)[i + 524288];
    us4 h, l;
    float a[4] = {v0.x + v1.x, v0.y + v1.y, v0.z + v1.z, v0.w + v1.w};
#pragma unroll
    for (int j = 0; j < 4; ++j) { h[j] = bfhi(a[j]); l[j] = bfhi(bfres(a[j])); }
    ((us4*)FQh)[i] = h;
    ((us4*)FQl)[i] = l;
}

// ---------- out combine: outm[b][c][a] = P0[c][ba] + P1[c][ba] + bf1[c]*L[ba] ----------
__global__ __launch_bounds__(256) void k_outcomb(const float* __restrict__ P,
    const float* __restrict__ bf1, const float* __restrict__ Lv,
    float* __restrict__ outm)
{
    int idx = blockIdx.x * 256 + threadIdx.x;          // 524288 total
    int c = idx >> 8;
    int ba0 = (idx & 255) * 4;
    float4 v0 = *(const float4*)&P[(size_t)c * 1024 + ba0];
    float4 v1 = *(const float4*)&P[2097152u + (size_t)c * 1024 + ba0];
    float4 lv = *(const float4*)&Lv[ba0];
    float bb = bf1[c];
    float4 o;
    o.x = v0.x + v1.x + bb * lv.x;
    o.y = v0.y + v1.y + bb * lv.y;
    o.z = v0.z + v1.z + bb * lv.z;
    o.w = v0.w + v1.w + bb * lv.w;
    *(float4*)&outm[(size_t)(ba0 >> 6) * (CCH * NA) + (size_t)c * NA + (ba0 & 63)] = o;
}

// ---------- qproj: barrier-free, A=queries fp32 [32768][512], B=WqT hi/lo [64][512] ----------
__global__ __launch_bounds__(256) void k_qproj(
    const float* __restrict__ A, const unsigned short* __restrict__ Bh,
    const unsigned short* __restrict__ Bl, const float* __restrict__ bq,
    unsigned short* __restrict__ Oh, unsigned short* __restrict__ Ol)
{
    const int tid = threadIdx.x, w = tid >> 6, l = tid & 63, lr = l & 15, lg = l >> 4;
    const int m16 = w & 1, n32 = w >> 1;
    const int m0 = blockIdx.x * 32;

    const float* pA = A + (size_t)(m0 + m16 * 16 + lr) * DQD + lg * 8;
    const size_t br0 = n32 * 32 + lr;
    const bf16x8* pB0h = (const bf16x8*)(Bh + br0 * DQD) + lg;
    const bf16x8* pB0l = (const bf16x8*)(Bl + br0 * DQD) + lg;
    const bf16x8* pB1h = (const bf16x8*)(Bh + (br0 + 16) * DQD) + lg;
    const bf16x8* pB1l = (const bf16x8*)(Bl + (br0 + 16) * DQD) + lg;

    f32x4 acc0 = {0.f, 0.f, 0.f, 0.f}, acc1 = {0.f, 0.f, 0.f, 0.f};
#pragma unroll 2
    for (int it = 0; it < 16; ++it) {
        float4 a0 = *(const float4*)pA;
        float4 a1 = *(const float4*)(pA + 4);
        pA += 32;
        bf16x8 ah, al_;
        float ar[8] = {a0.x, a0.y, a0.z, a0.w, a1.x, a1.y, a1.z, a1.w};
#pragma unroll
        for (int j = 0; j < 8; ++j) {
            ah[j] = (short)bfhi(ar[j]); al_[j] = (short)bfhi(bfres(ar[j]));
        }
        bf16x8 b0h = *pB0h, b0l = *pB0l;
        bf16x8 b1h = *pB1h, b1l = *pB1l;
        pB0h += 4; pB0l += 4; pB1h += 4; pB1l += 4;
        acc0 = MFMA(ah, b0h, acc0); acc0 = MFMA(ah, b0l, acc0); acc0 = MFMA(al_, b0h, acc0);
        acc1 = MFMA(ah, b1h, acc1); acc1 = MFMA(ah, b1l, acc1); acc1 = MFMA(al_, b1h, acc1);
    }

    const int mrow0 = m0 + m16 * 16 + lg * 4;
    const int b = mrow0 >> 11, cp0 = mrow0 & 2047;
#pragma unroll
    for (int nt = 0; nt < 2; ++nt) {
        f32x4 a = nt ? acc1 : acc0;
        int ac = n32 * 32 + nt * 16 + lr;
        float bb = bq[ac];
        us4 h, lo;
#pragma unroll
        for (int j = 0; j < 4; ++j) {
            float v = a[j] + bb;
            h[j] = bfhi(v); lo[j] = bfhi(bfres(v));
        }
        *(us4*)&Oh[(size_t)(b * 64 + ac) * CCH + cp0] = h;
        *(us4*)&Ol[(size_t)(b * 64 + ac) * CCH + cp0] = lo;
    }
}

// ---------- scores GEMM: partial = feat @ FQ, K-split x2, barrier-free ----------
__global__ __launch_bounds__(256) void k_scoremm(
    const float* __restrict__ feat, const unsigned short* __restrict__ FQh,
    const unsigned short* __restrict__ FQl, float* __restrict__ sp)
{
    const int tid = threadIdx.x, w = tid >> 6, l = tid & 63, lr = l & 15, lg = l >> 4;
    const int m16 = w & 1, n32 = w >> 1;
    const int m0 = blockIdx.x * 32, b = blockIdx.y, ks = blockIdx.z;
    const int koff = ks * 1024;

    const float* pA = feat + ((size_t)b * HWD + m0 + m16 * 16 + lr) * CCH + koff + lg * 8;
    const size_t br0 = (size_t)b * 64 + n32 * 32 + lr;
    const bf16x8* pB0h = (const bf16x8*)(FQh + br0 * CCH + koff) + lg;
    const bf16x8* pB0l = (const bf16x8*)(FQl + br0 * CCH + koff) + lg;
    const bf16x8* pB1h = (const bf16x8*)(FQh + (br0 + 16) * CCH + koff) + lg;
    const bf16x8* pB1l = (const bf16x8*)(FQl + (br0 + 16) * CCH + koff) + lg;

    f32x4 acc0 = {0.f, 0.f, 0.f, 0.f}, acc1 = {0.f, 0.f, 0.f, 0.f};
#pragma unroll 2
    for (int it = 0; it < 32; ++it) {
        float4 a0 = *(const float4*)pA;
        float4 a1 = *(const float4*)(pA + 4);
        pA += 32;
        bf16x8 ah, al_;
        float ar[8] = {a0.x, a0.y, a0.z, a0.w, a1.x, a1.y, a1.z, a1.w};
#pragma unroll
        for (int j = 0; j < 8; ++j) {
            ah[j] = (short)bfhi(ar[j]); al_[j] = (short)bfhi(bfres(ar[j]));
        }
        bf16x8 b0h = *pB0h, b0l = *pB0l;
        bf16x8 b1h = *pB1h, b1l = *pB1l;
        pB0h += 4; pB0l += 4; pB1h += 4; pB1l += 4;
        acc0 = MFMA(ah, b0h, acc0); acc0 = MFMA(ah, b0l, acc0); acc0 = MFMA(al_, b0h, acc0);
        acc1 = MFMA(ah, b1h, acc1); acc1 = MFMA(ah, b1l, acc1); acc1 = MFMA(al_, b1h, acc1);
    }

    float* spb = sp + ((size_t)(ks * 16 + b)) * (HWD * NA);
    const int nrow0 = m0 + m16 * 16 + lg * 4;
#pragma unroll
    for (int nt = 0; nt < 2; ++nt) {
        f32x4 a = nt ? acc1 : acc0;
        int ac = n32 * 32 + nt * 16 + lr;
#pragma unroll
        for (int j = 0; j < 4; ++j)
            spb[(size_t)(nrow0 + j) * NA + ac] = a[j];
    }
}

// ---------- bQ[ba] = sum_cp bf[cp] * Q[cp][ba] ----------
__global__ __launch_bounds__(256) void k_bq(const unsigned short* __restrict__ QTh,
    const unsigned short* __restrict__ QTl, const float* __restrict__ bf,
    float* __restrict__ bQ)
{
    const int row = blockIdx.x, tid = threadIdx.x;
    us8 h = *(const us8*)(QTh + (size_t)row * CCH + tid * 8);
    us8 l = *(const us8*)(QTl + (size_t)row * CCH + tid * 8);
    float s = 0.f;
#pragma unroll
    for (int j = 0; j < 8; ++j)
        s = fmaf(bf2f(h[j]) + bf2f(l[j]), bf[tid * 8 + j], s);
#pragma unroll
    for (int off = 1; off < 64; off <<= 1) s += __shfl_xor(s, off);
    __shared__ float ps[4];
    if ((tid & 63) == 0) ps[tid >> 6] = s;
    __syncthreads();
    if (tid == 0) bQ[row] = ps[0] + ps[1] + ps[2] + ps[3];
}

// ---------- softmax: attn fp32 (d_out) + attnT hi/lo + L partials ----------
__global__ __launch_bounds__(256) void k_softmax(
    const float* __restrict__ sp, const float* __restrict__ bQ,
    float* __restrict__ attn, unsigned short* __restrict__ ATh,
    unsigned short* __restrict__ ATl, float* __restrict__ part)
{
    __shared__ unsigned short tH[64][72], tL[64][72];
    __shared__ float red[4][64];
    const int tid = threadIdx.x, nc = blockIdx.x, b = blockIdx.y;
    const int r = tid >> 2, q = tid & 3;
    const size_t base = (((size_t)b) * HWD + nc * 64 + r) * NA + q * 16;
    const float* sp0 = sp + base;
    const float* sp1 = sp + (size_t)16 * HWD * NA + base;

    float v[16];
#pragma unroll
    for (int i = 0; i < 4; ++i) {
        float4 x0 = *(const float4*)(sp0 + i * 4);
        float4 x1 = *(const float4*)(sp1 + i * 4);
        float4 bb = *(const float4*)&bQ[b * 64 + q * 16 + i * 4];
        v[i * 4 + 0] = (x0.x + x1.x + bb.x) * 0.125f;
        v[i * 4 + 1] = (x0.y + x1.y + bb.y) * 0.125f;
        v[i * 4 + 2] = (x0.z + x1.z + bb.z) * 0.125f;
        v[i * 4 + 3] = (x0.w + x1.w + bb.w) * 0.125f;
    }
    float m = v[0];
#pragma unroll
    for (int i = 1; i < 16; ++i) m = fmaxf(m, v[i]);
    m = fmaxf(m, __shfl_xor(m, 1));
    m = fmaxf(m, __shfl_xor(m, 2));
    float s = 0.f;
#pragma unroll
    for (int i = 0; i < 16; ++i) { v[i] = expf(v[i] - m); s += v[i]; }
    s += __shfl_xor(s, 1);
    s += __shfl_xor(s, 2);
    float inv = 1.f / s;
    const size_t ob = (((size_t)b) * HWD + nc * 64 + r) * NA + q * 16;
#pragma unroll
    for (int i = 0; i < 4; ++i) {
        float4 o;
        o.x = v[i * 4 + 0] * inv; o.y = v[i * 4 + 1] * inv;
        o.z = v[i * 4 + 2] * inv; o.w = v[i * 4 + 3] * inv;
        *(float4*)&attn[ob + i * 4] = o;
    }
#pragma unroll
    for (int i = 0; i < 16; ++i) {
        float av = v[i] * inv;
        tH[q * 16 + i][r] = bfhi(av);
        tL[q * 16 + i][r] = bfhi(bfres(av));
    }
    __syncthreads();
    {
        int a2 = tid >> 2, seg = (tid & 3) * 16;
        us8 h0 = *(const us8*)&tH[a2][seg];
        us8 h1 = *(const us8*)&tH[a2][seg + 8];
        us8 l0 = *(const us8*)&tL[a2][seg];
        us8 l1 = *(const us8*)&tL[a2][seg + 8];
        size_t ro = ((size_t)b * 64 + a2) * HWD + nc * 64 + seg;
        *(us8*)&ATh[ro] = h0; *(us8*)&ATh[ro + 8] = h1;
        *(us8*)&ATl[ro] = l0; *(us8*)&ATl[ro + 8] = l1;
    }
    {
        int a3 = tid & 63, q3 = tid >> 6;
        float sL = 0.f;
#pragma unroll
        for (int rr = q3 * 16; rr < q3 * 16 + 16; ++rr)
            sL += bf2f(tH[a3][rr]) + bf2f(tL[a3][rr]);
        red[q3][a3] = sL;
        __syncthreads();
        if (q3 == 0)
            part[(size_t)nc * 1024 + b * 64 + a3] =
                red[0][a3] + red[1][a3] + red[2][a3] + red[3][a3];
    }
}

__global__ __launch_bounds__(64) void k_lsum2(const float* __restrict__ part,
                                              float* __restrict__ L)
{
    int ba = blockIdx.x * 64 + threadIdx.x;
    float s = 0.f;
#pragma unroll
    for (int g = 0; g < 16; ++g) s += part[(size_t)g * 1024 + ba];
    L[ba] = s;
}

// ---------- tmat: TT[ba][f] = (feat^T @ attn)^T per b; A via padded LDS transpose ----------
__global__ __launch_bounds__(256) void k_tmat(
    const float* __restrict__ feat, const unsigned short* __restrict__ ATh,
    const unsigned short* __restrict__ ATl,
    unsigned short* __restrict__ TTh, unsigned short* __restrict__ TTl)
{
    __shared__ float At[2][32 * 33];
    const int tid = threadIdx.x, w = tid >> 6, l = tid & 63, lr = l & 15, lg = l >> 4;
    const int m16 = w & 1, n32 = w >> 1;
    const int f0 = blockIdx.x * 32, b = blockIdx.y;
    const int kr = tid >> 3, c4 = (tid & 7) * 4;

    const float* G = feat + (size_t)b * HWD * CCH;
    const size_t br0 = (size_t)b * 64 + n32 * 32 + lr;
    const bf16x8* pB0h = (const bf16x8*)(ATh + br0 * HWD) + lg;
    const bf16x8* pB0l = (const bf16x8*)(ATl + br0 * HWD) + lg;
    const bf16x8* pB1h = (const bf16x8*)(ATh + (br0 + 16) * HWD) + lg;
    const bf16x8* pB1l = (const bf16x8*)(ATl + (br0 + 16) * HWD) + lg;

    f32x4 acc0 = {0.f, 0.f, 0.f, 0.f}, acc1 = {0.f, 0.f, 0.f, 0.f};

    {
        float4 g = *(const float4*)&G[(size_t)kr * CCH + f0 + c4];
        At[0][kr * 33 + c4 + 0] = g.x; At[0][kr * 33 + c4 + 1] = g.y;
        At[0][kr * 33 + c4 + 2] = g.z; At[0][kr * 33 + c4 + 3] = g.w;
    }
    int cur = 0;
    for (int it = 0; it < 32; ++it) {
        float4 gn = {0.f, 0.f, 0.f, 0.f};
        if (it < 31)
            gn = *(const float4*)&G[(size_t)((it + 1) * 32 + kr) * CCH + f0 + c4];
        __syncthreads();
        float av[8];
#pragma unroll
        for (int j = 0; j < 8; ++j)
            av[j] = At[cur][(lg * 8 + j) * 33 + m16 * 16 + lr];
        bf16x8 ah, al_;
#pragma unroll
        for (int j = 0; j < 8; ++j) {
            ah[j] = (short)bfhi(av[j]); al_[j] = (short)bfhi(bfres(av[j]));
        }
        bf16x8 b0h = *pB0h, b0l = *pB0l;
        bf16x8 b1h = *pB1h, b1l = *pB1l;
        pB0h += 4; pB0l += 4; pB1h += 4; pB1l += 4;
        acc0 = MFMA(ah, b0h, acc0); acc0 = MFMA(ah, b0l, acc0); acc0 = MFMA(al_, b0h, acc0);
        acc1 = MFMA(ah, b1h, acc1); acc1 = MFMA(ah, b1l, acc1); acc1 = MFMA(al_, b1h, acc1);
        __syncthreads();
        if (it < 31) {
            At[cur ^ 1][kr * 33 + c4 + 0] = gn.x; At[cur ^ 1][kr * 33 + c4 + 1] = gn.y;
            At[cur ^ 1][kr * 33 + c4 + 2] = gn.z; At[cur ^ 1][kr * 33 + c4 + 3] = gn.w;
        }
        cur ^= 1;
    }

    const int mrow0 = f0 + m16 * 16 + lg * 4;
#pragma unroll
    for (int nt = 0; nt < 2; ++nt) {
        f32x4 a = nt ? acc1 : acc0;
        int ac = n32 * 32 + nt * 16 + lr;
        us4 h, lo;
#pragma unroll
        for (int j = 0; j < 4; ++j) { h[j] = bfhi(a[j]); lo[j] = bfhi(bfres(a[j])); }
        *(us4*)&TTh[(size_t)(b * 64 + ac) * CCH + mrow0] = h;
        *(us4*)&TTl[(size_t)(b * 64 + ac) * CCH + mrow0] = lo;
    }
}

extern "C" void kernel_launch(void* const* d_in, const int* in_sizes, int n_in,
                              void* d_out, int out_size, void* d_ws, size_t ws_size,
                              hipStream_t stream)
{
    (void)in_sizes; (void)n_in; (void)out_size; (void)ws_size;
    const float* queries  = (const float*)d_in[0];
    const float* features = (const float*)d_in[1];
    const float* Wq  = (const float*)d_in[2];
    const float* bq  = (const float*)d_in[3];
    const float* Wf  = (const float*)d_in[4];
    const float* bf  = (const float*)d_in[5];
    const float* Wf1 = (const float*)d_in[6];
    const float* bf1 = (const float*)d_in[7];
    float* out = (float*)d_out;
    char*  W   = (char*)d_ws;

    const size_t MB = 1u << 20;
    unsigned short* QTh  = (unsigned short*)(W);             // [1024][2048] 4MB
    unsigned short* QTl  = (unsigned short*)(W + 4 * MB);
    unsigned short* FQh  = (unsigned short*)(W + 8 * MB);    // [1024][2048] 4MB
    unsigned short* FQl  = (unsigned short*)(W + 12 * MB);
    unsigned short* WfH  = (unsigned short*)(W + 16 * MB);   // [2048][2048] 8MB
    unsigned short* WfL  = (unsigned short*)(W + 24 * MB);
    unsigned short* W1TH = (unsigned short*)(W + 32 * MB);   // [c][f] 8MB
    unsigned short* W1TL = (unsigned short*)(W + 40 * MB);
    unsigned short* TTh  = (unsigned short*)(W + 48 * MB);   // [1024][2048] 4MB
    unsigned short* TTl  = (unsigned short*)(W + 52 * MB);
    unsigned short* ATh  = (unsigned short*)(W + 56 * MB);   // [1024][1024] 2MB
    unsigned short* ATl  = (unsigned short*)(W + 58 * MB);
    float* sp   = (float*)(W + 60 * MB);                     // [2][16][1024][64] 8MB
    float* P    = (float*)(W + 68 * MB);                     // [2][1024][2048] fp32 16MB
    unsigned short* WqTh = (unsigned short*)(W + 84 * MB);   // [64][512] 64KB
    unsigned short* WqTl = (unsigned short*)(W + 84 * MB + 65536);
    float* bQ   = (float*)(W + 84 * MB + 131072);            // 4KB
    float* L    = (float*)(W + 84 * MB + 131072 + 4096);
    float* part = (float*)(W + 84 * MB + 131072 + 8192);     // [16][1024] 64KB

    float* attn = out;              // d_out[0 .. 1M)  fp32 [b][n][a]
    float* outm = out + 1048576;    // d_out[1M .. 3M) fp32 [b][c][a]

    // converts
    k_convWf<<<dim3(4096), 256, 0, stream>>>(Wf, WfH, WfL);
    k_convT <<<dim3(32, 32), 256, 0, stream>>>(Wf1, W1TH, W1TL);
    k_convWq<<<dim3(8), 256, 0, stream>>>(Wq, WqTh, WqTl);
    // QT = (queries @ Wq + bq)^T
    k_qproj<<<dim3(1024), 256, 0, stream>>>(queries, WqTh, WqTl, bq, QTh, QTl);
    // bQ = bf . Q
    k_bq<<<dim3(1024), 256, 0, stream>>>(QTh, QTl, bf, bQ);
    // FQ = Wf @ Q  (K-split x2 -> P, then combine -> FQT hi/lo)
    k_gemm_ks<0><<<dim3(32, 8, 2), 256, 0, stream>>>(WfH, WfL, QTh, QTl, P);
    k_fqcomb<<<dim3(2048), 256, 0, stream>>>(P, FQh, FQl);
    // scores partials (K-split x2)
    k_scoremm<<<dim3(32, 16, 2), 256, 0, stream>>>(features, FQh, FQl, sp);
    // softmax -> attn, attnT, L partials
    k_softmax<<<dim3(16, 16), 256, 0, stream>>>(sp, bQ, attn, ATh, ATl, part);
    k_lsum2<<<dim3(16), 64, 0, stream>>>(part, L);
    // TT = (feat^T @ attn)^T per b
    k_tmat<<<dim3(64, 16), 256, 0, stream>>>(features, ATh, ATl, TTh, TTl);
    // out = Wf1^T @ T + bf1 (x) L  (K-split x2 -> P, then combine)
    k_gemm_ks<1><<<dim3(32, 8, 2), 256, 0, stream>>>(W1TH, W1TL, TTh, TTl, P);
    k_outcomb<<<dim3(2048), 256, 0, stream>>>(P, bf1, L, outm);
}